// Round 10
// baseline (736.986 us; speedup 1.0000x reference)
//
#include <hip/hip_runtime.h>

// GCN 3-layer forward on MI355X.
// Pipeline (A_hat (X W) = (A_hat X) W):
//   aggx:  Y1 = A_hat X          GEMM1: H1s = dinv*relu(Y1 W1 + b1)
//   agg256s: Y2 = A_hat H1       MLP23: G3 = dinv*((relu(Y2 W2 + b2)) W3)  [fused]
//   aggouts: out = dinv[c]*(sum G3[r]+G3[c]) + b3 (f32)
// Gather wall (r0-r8): L2-fill path ~3.3-3.8 TB/s; FETCH bytes are the lever.
// Fetch granule 128B (r4). XCD cell map bid&7 (r3/r6-validated, reads+writes).
// Per-XCD gather slab = 12.8MB (sources x 128B chunk) vs 4MiB L2 -> ~2.5x
// compulsory refetch; r7 seg-loops failed (drift), coop-sync rejected (sync
// cost ~= gain, graph-capture risk).
// r9/r10: L2 capacity relief. (a) NT hints: rowidx loads + output stores in
// all 3 gathers are non-temporal (zero-reuse streams stop evicting the
// reusable slab); epart stores NT via long-long bitcast (r9 compile fix:
// builtin rejects HIP vector types). (b) count fused into k_part flush ->
// k_count8 deleted (-1 launch, -12.8MB epart re-read). Gather loads stay
// default-cached (they carry the reuse).
// k_part: block radix partition by dest-eighth, LDS-staged, compacted runs.
// k_fill8p: cell reads its partition, writes its rowidx region (XCD-local,
// full-line writeback; r6-proven). rowidx writes NOT NT (L2 must accumulate).
// MLP23 fusion: H2 tile in LDS (XOR-swizzle (row&7)<<4); W3 L2-resident.

#define IN_F 50
#define HID  256
#define OUT_F 121
#define KP1  64      // layer-1 width padded 50->64
#define NP3  128     // layer-3 N padded 121->128
#define MPAD 100096  // 782 * 128

typedef __attribute__((ext_vector_type(8))) short bf16x8;
typedef __attribute__((ext_vector_type(4))) float f32x4;

__device__ __forceinline__ float bf2f(unsigned short u) {
    union { unsigned int i; float f; } x; x.i = ((unsigned int)u) << 16; return x.f;
}
__device__ __forceinline__ unsigned short f2bf(float f) {
    union { float f; unsigned int i; } x; x.f = f;
    unsigned int r = x.i + 0x7FFFu + ((x.i >> 16) & 1u);  // RNE
    return (unsigned short)(r >> 16);
}

__device__ __forceinline__ void gl2lds16(const void* g, void* l) {
    __builtin_amdgcn_global_load_lds(
        (const __attribute__((address_space(1))) void*)g,
        (__attribute__((address_space(3))) void*)l, 16, 0, 0);
}

// ---- edge dtype detection (int64 vs int32), 64-lane parallel ----------------
__global__ void k_detect(const int* __restrict__ ei, int* __restrict__ flag, int N) {
    int i = threadIdx.x;
    int lo = ei[2 * i], hi = ei[2 * i + 1];
    int bad = (hi != 0) || ((unsigned)lo >= (unsigned)N);
    unsigned long long m = __ballot(bad);
    if (threadIdx.x == 0) *flag = (m == 0ULL) ? 1 : 0;
}

// ---- k_part: radix partition of edges by dest-eighth + fused dest count -----
// 2048 edges/block via LDS; compacted flushes (~2KB runs -> full-line writes).
__global__ __launch_bounds__(256) void k_part(const int* __restrict__ ei,
                                              const int* __restrict__ flag,
                                              int2* __restrict__ epart,
                                              int* __restrict__ pcnt,
                                              int* __restrict__ cnt,
                                              int E, int N, int rng, int partcap) {
    __shared__ int2 eb[2048];
    __shared__ int hist[8], base[8], cur[8];
    int tid = threadIdx.x;
    if (tid < 8) { hist[tid] = 0; cur[tid] = 0; }
    __syncthreads();
    int f = *flag;
    int t0 = blockIdx.x * 2048;
    #pragma unroll
    for (int j = 0; j < 8; j++) {
        int t = t0 + j * 256 + tid;
        int2 e = make_int2(-1, -1);
        if (t < E) {
            int c = f ? ei[2 * (E + t)] : ei[E + t];
            int r = f ? ei[2 * t] : ei[t];
            e.x = min(max(c, 0), N - 1);
            e.y = min(max(r, 0), N - 1);
            atomicAdd(&hist[e.x / rng], 1);
        }
        eb[j * 256 + tid] = e;
    }
    __syncthreads();
    if (tid < 8) base[tid] = atomicAdd(&pcnt[tid], hist[tid]);
    __syncthreads();
    #pragma unroll
    for (int j = 0; j < 8; j++) {
        int2 e = eb[j * 256 + tid];
        if (e.x >= 0) {
            int rg = e.x / rng;
            int p = base[rg] + atomicAdd(&cur[rg], 1);
            if (p < partcap) {
                long long ev;
                __builtin_memcpy(&ev, &e, 8);
                __builtin_nontemporal_store(ev, (long long*)&epart[(size_t)rg * partcap + p]);
                atomicAdd(&cnt[e.x], 1);
            }
        }
    }
}

// ---- 3-phase parallel scan over cnt[N] --------------------------------------
__global__ __launch_bounds__(1024) void k_scanA(const int* __restrict__ cnt,
                                                int* __restrict__ bsum, int n) {
    __shared__ int ws[16];
    int tid = threadIdx.x, lane = tid & 63, wid = tid >> 6;
    int i0 = blockIdx.x * 4096 + tid * 4;
    int t = 0;
    #pragma unroll
    for (int j = 0; j < 4; j++) t += (i0 + j < n) ? cnt[i0 + j] : 0;
    #pragma unroll
    for (int d = 1; d < 64; d <<= 1) t += __shfl_xor(t, d, 64);
    if (lane == 0) ws[wid] = t;
    __syncthreads();
    if (tid == 0) {
        int s = 0;
        #pragma unroll
        for (int j = 0; j < 16; j++) s += ws[j];
        bsum[blockIdx.x] = s;
    }
}

__global__ void k_scanB(const int* __restrict__ bsum, int* __restrict__ bbase,
                        int* __restrict__ offs, int nb, int n) {
    int lane = threadIdx.x;
    int v = (lane < nb) ? bsum[lane] : 0;
    int x = v;
    #pragma unroll
    for (int d = 1; d < 64; d <<= 1) { int y = __shfl_up(x, d, 64); if (lane >= d) x += y; }
    if (lane < nb) bbase[lane] = x - v;
    if (lane == nb - 1) offs[n] = x;
}

__global__ __launch_bounds__(1024) void k_scanC(const int* __restrict__ cnt,
                                                const int* __restrict__ bbase,
                                                int* __restrict__ offs,
                                                float* __restrict__ dinv, int n) {
    __shared__ int wsum[16];
    int tid = threadIdx.x, lane = tid & 63, wid = tid >> 6;
    int i0 = blockIdx.x * 4096 + tid * 4;
    int v0 = (i0 + 0 < n) ? cnt[i0 + 0] : 0;
    int v1 = (i0 + 1 < n) ? cnt[i0 + 1] : 0;
    int v2 = (i0 + 2 < n) ? cnt[i0 + 2] : 0;
    int v3 = (i0 + 3 < n) ? cnt[i0 + 3] : 0;
    int s1 = v0 + v1, s2 = s1 + v2, tsum = s2 + v3;
    int x = tsum;
    #pragma unroll
    for (int d = 1; d < 64; d <<= 1) { int y = __shfl_up(x, d, 64); if (lane >= d) x += y; }
    if (lane == 63) wsum[wid] = x;
    __syncthreads();
    int wpre = 0;
    #pragma unroll
    for (int j = 0; j < 16; j++) wpre += (j < wid) ? wsum[j] : 0;
    int e0 = bbase[blockIdx.x] + wpre + x - tsum;
    if (i0 + 0 < n) { offs[i0+0] = e0;      dinv[i0+0] = rsqrtf((float)(v0 + 1)); }
    if (i0 + 1 < n) { offs[i0+1] = e0 + v0; dinv[i0+1] = rsqrtf((float)(v1 + 1)); }
    if (i0 + 2 < n) { offs[i0+2] = e0 + s1; dinv[i0+2] = rsqrtf((float)(v2 + 1)); }
    if (i0 + 3 < n) { offs[i0+3] = e0 + s2; dinv[i0+3] = rsqrtf((float)(v3 + 1)); }
}

// ---- fill: cell = bid&7 reads its partition, writes its rowidx region -------
__global__ void k_fill8p(const int2* __restrict__ epart, const int* __restrict__ pcnt,
                         const int* __restrict__ offs, int* __restrict__ fillc,
                         int* __restrict__ rowidx, int E, int partcap) {
    int cell = blockIdx.x & 7;
    int t = (blockIdx.x >> 3) * blockDim.x + threadIdx.x;
    if (t >= min(pcnt[cell], partcap)) return;
    int2 e = epart[(size_t)cell * partcap + t];
    int pos = offs[e.x] + atomicAdd(&fillc[e.x], 1);
    if ((unsigned)pos < (unsigned)E) rowidx[pos] = e.y;
}

// ---- input prep (padx + 3 weight transposes, one launch) --------------------
__global__ void k_prep(const float* __restrict__ x, const float* __restrict__ dinv,
                       unsigned short* __restrict__ Xs,
                       const float* __restrict__ W1, unsigned short* __restrict__ Bt1,
                       const float* __restrict__ W2, unsigned short* __restrict__ Bt2,
                       const float* __restrict__ W3, unsigned short* __restrict__ Bt3,
                       int N) {
    int bid = blockIdx.x;
    int npadx = (N * KP1 + 255) / 256;
    if (bid < npadx) {
        int idx = bid * 256 + (int)threadIdx.x;
        if (idx < N * KP1) {
            int node = idx >> 6, k = idx & 63;
            Xs[idx] = (k < IN_F) ? f2bf(dinv[node] * x[node * IN_F + k]) : (unsigned short)0;
        }
        return;
    }
    bid -= npadx;
    if (bid < (HID * KP1) / 256) {          // Bt1 [256][64]
        int idx = bid * 256 + (int)threadIdx.x;
        int nn = idx >> 6, k = idx & 63;
        Bt1[idx] = (k < IN_F) ? f2bf(W1[k * HID + nn]) : (unsigned short)0;
        return;
    }
    bid -= (HID * KP1) / 256;
    if (bid < (HID * HID) / 256) {          // Bt2 [256][256]
        int idx = bid * 256 + (int)threadIdx.x;
        int nn = idx >> 8, k = idx & 255;
        Bt2[idx] = f2bf(W2[k * HID + nn]);
        return;
    }
    bid -= (HID * HID) / 256;
    {                                        // Bt3 [128][256]
        int idx = bid * 256 + (int)threadIdx.x;
        int nn = idx >> 8, k = idx & 255;
        Bt3[idx] = (nn < OUT_F) ? f2bf(W3[k * OUT_F + nn]) : (unsigned short)0;
    }
}

// ---- LDS-tiled GEMM (m97 structure) — layer 1 only --------------------------
__global__ __launch_bounds__(256) void k_gemm_lds(const unsigned short* __restrict__ A,
                                                  const unsigned short* __restrict__ Bt,
                                                  const float* __restrict__ dinv,
                                                  const float* __restrict__ bias,
                                                  unsigned short* __restrict__ C,
                                                  int K, int Nout,
                                                  int BIAS, int RELU, int SCALE) {
    __shared__ char lds[16384];   // A tile [128][32] bf16 @0, B tile @8192
    const int tid = threadIdx.x;
    const int wid = tid >> 6, lane = tid & 63;
    const int wm = wid & 1, wn = wid >> 1;
    const int quad = lane >> 4, ml = lane & 15;
    const int m0 = blockIdx.x * 128;
    const int n0g = blockIdx.y * 128;

    f32x4 acc[4][4];
    #pragma unroll
    for (int a = 0; a < 4; a++)
        #pragma unroll
        for (int b = 0; b < 4; b++) acc[a][b] = (f32x4){0.f, 0.f, 0.f, 0.f};

    for (int kk = 0; kk < K; kk += 32) {
        #pragma unroll
        for (int r = 0; r < 2; r++) {
            int c = r * 256 + tid;
            int row = c >> 2, q = c & 3;
            gl2lds16(A  + (size_t)(m0  + row) * K + kk + q * 8, lds + c * 16);
            gl2lds16(Bt + (size_t)(n0g + row) * K + kk + q * 8, lds + 8192 + c * 16);
        }
        __syncthreads();
        bf16x8 af[4], bfv[4];
        #pragma unroll
        for (int mf = 0; mf < 4; mf++)
            af[mf] = *(const bf16x8*)(lds + ((wm * 64 + mf * 16 + ml) * 64 + quad * 16));
        #pragma unroll
        for (int nf = 0; nf < 4; nf++)
            bfv[nf] = *(const bf16x8*)(lds + 8192 + ((wn * 64 + nf * 16 + ml) * 64 + quad * 16));
        #pragma unroll
        for (int mf = 0; mf < 4; mf++)
            #pragma unroll
            for (int nf = 0; nf < 4; nf++)
                acc[mf][nf] = __builtin_amdgcn_mfma_f32_16x16x32_bf16(af[mf], bfv[nf], acc[mf][nf], 0, 0, 0);
        __syncthreads();
    }

    #pragma unroll
    for (int mf = 0; mf < 4; mf++) {
        int r0 = m0 + wm * 64 + mf * 16 + quad * 4;
        float dd[4] = {1.f, 1.f, 1.f, 1.f};
        if (SCALE) { dd[0]=dinv[r0]; dd[1]=dinv[r0+1]; dd[2]=dinv[r0+2]; dd[3]=dinv[r0+3]; }
        #pragma unroll
        for (int nf = 0; nf < 4; nf++) {
            int col = n0g + wn * 64 + nf * 16 + ml;
            float bb = BIAS ? bias[col] : 0.f;
            #pragma unroll
            for (int i = 0; i < 4; i++) {
                float v = acc[mf][nf][i] + bb;
                if (RELU) v = fmaxf(v, 0.f);
                v *= dd[i];
                C[(size_t)(r0 + i) * Nout + col] = f2bf(v);
            }
        }
    }
}

// ---- FUSED GEMM2+GEMM3: G3 = dinv * (relu(Y2 W2 + b2) W3) -------------------
__global__ __launch_bounds__(256) void k_mlp23(const unsigned short* __restrict__ A,
                                               const unsigned short* __restrict__ B2t,
                                               const unsigned short* __restrict__ B3t,
                                               const float* __restrict__ b2,
                                               const float* __restrict__ dinv,
                                               unsigned short* __restrict__ G) {
    __shared__ char lds[65536];  // phase1 staging: A[128][32]@0, B2[256][32]@8192 (24KB)
                                 // then H2 [128][256] bf16 @0 (64KB, swizzled)
    const int tid = threadIdx.x;
    const int wid = tid >> 6, lane = tid & 63;
    const int wm = wid & 1, wn = wid >> 1;
    const int quad = lane >> 4, ml = lane & 15;
    const int m0 = blockIdx.x * 128;

    f32x4 acc1[4][8];
    #pragma unroll
    for (int a = 0; a < 4; a++)
        #pragma unroll
        for (int b = 0; b < 8; b++) acc1[a][b] = (f32x4){0.f, 0.f, 0.f, 0.f};

    for (int kk = 0; kk < HID; kk += 32) {
        #pragma unroll
        for (int r = 0; r < 2; r++) {
            int c = r * 256 + tid;
            int row = c >> 2, q = c & 3;
            gl2lds16(A + (size_t)(m0 + row) * HID + kk + q * 8, lds + c * 16);
        }
        #pragma unroll
        for (int r = 0; r < 4; r++) {
            int c = r * 256 + tid;
            int nn = c >> 2, q = c & 3;
            gl2lds16(B2t + (size_t)nn * HID + kk + q * 8, lds + 8192 + c * 16);
        }
        __syncthreads();
        bf16x8 af[4], bv[8];
        #pragma unroll
        for (int mf = 0; mf < 4; mf++)
            af[mf] = *(const bf16x8*)(lds + ((wm * 64 + mf * 16 + ml) * 64 + quad * 16));
        #pragma unroll
        for (int nf = 0; nf < 8; nf++)
            bv[nf] = *(const bf16x8*)(lds + 8192 + ((wn * 128 + nf * 16 + ml) * 64 + quad * 16));
        #pragma unroll
        for (int mf = 0; mf < 4; mf++)
            #pragma unroll
            for (int nf = 0; nf < 8; nf++)
                acc1[mf][nf] = __builtin_amdgcn_mfma_f32_16x16x32_bf16(af[mf], bv[nf], acc1[mf][nf], 0, 0, 0);
        __syncthreads();
    }

    // H2 = relu(acc1 + b2) -> LDS bf16, swizzled byte ^= (row&7)<<4
    #pragma unroll
    for (int nf = 0; nf < 8; nf++) {
        int col = wn * 128 + nf * 16 + ml;
        float bb = b2[col];
        #pragma unroll
        for (int mf = 0; mf < 4; mf++) {
            int rl = wm * 64 + mf * 16 + quad * 4;
            #pragma unroll
            for (int i = 0; i < 4; i++) {
                int row = rl + i;
                int byte = (row * 512 + col * 2) ^ ((row & 7) << 4);
                *(unsigned short*)(lds + byte) = f2bf(fmaxf(acc1[mf][nf][i] + bb, 0.f));
            }
        }
    }
    __syncthreads();

    // phase 2: G3 tile (128x128), A from H2-LDS, B direct from global Bt3
    f32x4 acc2[4][4];
    #pragma unroll
    for (int a = 0; a < 4; a++)
        #pragma unroll
        for (int b = 0; b < 4; b++) acc2[a][b] = (f32x4){0.f, 0.f, 0.f, 0.f};

    for (int kk = 0; kk < HID; kk += 32) {
        bf16x8 af2[4], bv2[4];
        #pragma unroll
        for (int mf = 0; mf < 4; mf++) {
            int row = wm * 64 + mf * 16 + ml;
            int byte = (row * 512 + kk * 2 + quad * 16) ^ ((row & 7) << 4);
            af2[mf] = *(const bf16x8*)(lds + byte);
        }
        #pragma unroll
        for (int nf = 0; nf < 4; nf++)
            bv2[nf] = *(const bf16x8*)(B3t + (size_t)(wn * 64 + nf * 16 + ml) * HID + kk + quad * 8);
        #pragma unroll
        for (int mf = 0; mf < 4; mf++)
            #pragma unroll
            for (int nf = 0; nf < 4; nf++)
                acc2[mf][nf] = __builtin_amdgcn_mfma_f32_16x16x32_bf16(af2[mf], bv2[nf], acc2[mf][nf], 0, 0, 0);
    }

    #pragma unroll
    for (int mf = 0; mf < 4; mf++) {
        int r0 = m0 + wm * 64 + mf * 16 + quad * 4;
        float dd[4] = {dinv[r0], dinv[r0+1], dinv[r0+2], dinv[r0+3]};
        #pragma unroll
        for (int nf = 0; nf < 4; nf++) {
            int col = wn * 64 + nf * 16 + ml;
            #pragma unroll
            for (int i = 0; i < 4; i++)
                G[(size_t)(r0 + i) * NP3 + col] = f2bf(acc2[mf][nf][i] * dd[i]);
        }
    }
}

// ---- aggregation kernels ----------------------------------------------------
// 16B/lane gathers, masked unroll-4 edge loop. NT: rowidx loads + output
// stores (zero-reuse streams bypass L2 retention; slab keeps the capacity).

__device__ __forceinline__ void nt_store_bf16x8(bf16x8 v, unsigned short* p) {
    // bf16x8 = 16B; store as two long longs (NT builtin rejects vector types).
    long long lo, hi;
    __builtin_memcpy(&lo, &v, 8);
    __builtin_memcpy(&hi, ((const char*)&v) + 8, 8);
    __builtin_nontemporal_store(lo, (long long*)p);
    __builtin_nontemporal_store(hi, (long long*)(p + 4));
}

// aggx: rows 64 bf16 = 128B (1 line, no split) -> 8 lanes/row, 8 nodes/wave.
__global__ void k_aggx(const unsigned short* __restrict__ Xs,
                       const int* __restrict__ offs, const int* __restrict__ rowidx,
                       const float* __restrict__ dinv, unsigned short* __restrict__ Y, int N) {
    int wid = threadIdx.x >> 6, lane = threadIdx.x & 63;
    int sub = lane >> 3, sl = lane & 7;
    int node = blockIdx.x * 32 + wid * 8 + sub;
    int nc = min(node, N - 1);
    int c = sl * 8;
    bf16x8 s = *(const bf16x8*)(Xs + (size_t)nc * KP1 + c);
    float a[8];
    #pragma unroll
    for (int k = 0; k < 8; k++) a[k] = bf2f((unsigned short)s[k]);
    int e = offs[nc], end = offs[nc + 1];
    if (node >= N) { e = 0; end = 0; }
    while (__any(e < end)) {
        int r[4]; float m[4];
        #pragma unroll
        for (int j = 0; j < 4; j++) {
            int idx = e + j;
            m[j] = (idx < end) ? 1.f : 0.f;
            idx = min(idx, end - 1); idx = max(idx, 0);
            r[j] = __builtin_nontemporal_load(&rowidx[idx]);
        }
        bf16x8 u[4];
        #pragma unroll
        for (int j = 0; j < 4; j++)
            u[j] = *(const bf16x8*)(Xs + (size_t)r[j] * KP1 + c);
        #pragma unroll
        for (int j = 0; j < 4; j++)
            #pragma unroll
            for (int k = 0; k < 8; k++)
                a[k] = fmaf(bf2f((unsigned short)u[j][k]), m[j], a[k]);
        e += 4;
    }
    if (node < N) {
        float dv = dinv[node];
        bf16x8 o;
        #pragma unroll
        for (int k = 0; k < 8; k++) o[k] = (short)f2bf(a[k] * dv);
        nt_store_bf16x8(o, Y + (size_t)node * KP1 + c);
    }
}

// agg256s: FEATURE-SPLIT gather, 256-wide rows. 4 chunks of 64 bf16 (128B line);
// cell = bid&7: chunk = cell>>1, dest-half = cell&1. 8 lanes/chunk-row,
// 8 nodes/wave, 32/block. Per-XCD slab 12.8MB (r6-proven: 107us, FETCH ~329MB).
__global__ void k_agg256s(const unsigned short* __restrict__ Hn,
                          const int* __restrict__ offs, const int* __restrict__ rowidx,
                          const float* __restrict__ dinv, unsigned short* __restrict__ Y,
                          int N, int half_n) {
    int cell = blockIdx.x & 7;
    int chunk = cell >> 1, half = cell & 1;
    int idx = blockIdx.x >> 3;
    int wid = threadIdx.x >> 6, lane = threadIdx.x & 63;
    int sub = lane >> 3, sl = lane & 7;
    int node = half * half_n + idx * 32 + wid * 8 + sub;
    int hi_end = min((half + 1) * half_n, N);
    int ok = node < hi_end;
    int nc = ok ? node : hi_end - 1;
    int c = chunk * 64 + sl * 8;
    bf16x8 s = *(const bf16x8*)(Hn + (size_t)nc * HID + c);
    float a[8];
    #pragma unroll
    for (int k = 0; k < 8; k++) a[k] = bf2f((unsigned short)s[k]);
    int e = offs[nc], end = offs[nc + 1];
    if (!ok) { e = 0; end = 0; }
    while (__any(e < end)) {
        int r[4]; float m[4];
        #pragma unroll
        for (int j = 0; j < 4; j++) {
            int idx2 = e + j;
            m[j] = (idx2 < end) ? 1.f : 0.f;
            idx2 = min(idx2, end - 1); idx2 = max(idx2, 0);
            r[j] = __builtin_nontemporal_load(&rowidx[idx2]);
        }
        bf16x8 u[4];
        #pragma unroll
        for (int j = 0; j < 4; j++)
            u[j] = *(const bf16x8*)(Hn + (size_t)r[j] * HID + c);
        #pragma unroll
        for (int j = 0; j < 4; j++)
            #pragma unroll
            for (int k = 0; k < 8; k++)
                a[k] = fmaf(bf2f((unsigned short)u[j][k]), m[j], a[k]);
        e += 4;
    }
    if (ok) {
        float dv = dinv[node];
        bf16x8 o;
        #pragma unroll
        for (int k = 0; k < 8; k++) o[k] = (short)f2bf(a[k] * dv);
        nt_store_bf16x8(o, Y + (size_t)node * HID + c);
    }
}

// aggouts: FEATURE-SPLIT gather, 128-wide rows. 2 chunks of 64 bf16 (128B line)
// x 4 dest-quarters; cell = bid&7: chunk = cell>>2, quarter = cell&3.
__global__ void k_aggouts(const unsigned short* __restrict__ G,
                          const int* __restrict__ offs, const int* __restrict__ rowidx,
                          const float* __restrict__ dinv, const float* __restrict__ bias,
                          float* __restrict__ out, int N, int quar_n) {
    int cell = blockIdx.x & 7;
    int chunk = cell >> 2, quar = cell & 3;
    int idx = blockIdx.x >> 3;
    int wid = threadIdx.x >> 6, lane = threadIdx.x & 63;
    int sub = lane >> 3, sl = lane & 7;
    int node = quar * quar_n + idx * 32 + wid * 8 + sub;
    int hi_end = min((quar + 1) * quar_n, N);
    int ok = node < hi_end;
    int nc = ok ? node : hi_end - 1;
    int c = chunk * 64 + sl * 8;
    bf16x8 s = *(const bf16x8*)(G + (size_t)nc * NP3 + c);
    float a[8];
    #pragma unroll
    for (int k = 0; k < 8; k++) a[k] = bf2f((unsigned short)s[k]);
    int e = offs[nc], end = offs[nc + 1];
    if (!ok) { e = 0; end = 0; }
    while (__any(e < end)) {
        int r[4]; float m[4];
        #pragma unroll
        for (int j = 0; j < 4; j++) {
            int idx2 = e + j;
            m[j] = (idx2 < end) ? 1.f : 0.f;
            idx2 = min(idx2, end - 1); idx2 = max(idx2, 0);
            r[j] = __builtin_nontemporal_load(&rowidx[idx2]);
        }
        bf16x8 u[4];
        #pragma unroll
        for (int j = 0; j < 4; j++)
            u[j] = *(const bf16x8*)(G + (size_t)r[j] * NP3 + c);
        #pragma unroll
        for (int j = 0; j < 4; j++)
            #pragma unroll
            for (int k = 0; k < 8; k++)
                a[k] = fmaf(bf2f((unsigned short)u[j][k]), m[j], a[k]);
        e += 4;
    }
    if (ok) {
        float dv = dinv[node];
        #pragma unroll
        for (int k = 0; k < 8; k++) {
            int col = c + k;
            if (col < OUT_F)
                __builtin_nontemporal_store(fmaf(a[k], dv, bias[col]),
                                            &out[(size_t)node * OUT_F + col]);
        }
    }
}

// ---- launch -----------------------------------------------------------------

extern "C" void kernel_launch(void* const* d_in, const int* in_sizes, int n_in,
                              void* d_out, int out_size, void* d_ws, size_t ws_size,
                              hipStream_t stream) {
    const float* x  = (const float*)d_in[0];
    const int*   ei = (const int*)d_in[1];
    const float* W1 = (const float*)d_in[2];
    const float* b1 = (const float*)d_in[3];
    const float* W2 = (const float*)d_in[4];
    const float* b2 = (const float*)d_in[5];
    const float* W3 = (const float*)d_in[6];
    const float* b3 = (const float*)d_in[7];
    float* out = (float*)d_out;

    const int N = in_sizes[0] / IN_F;     // 100000
    const int E = in_sizes[1] / 2;        // 1600000

    char* w = (char*)d_ws;
    size_t off = 0;
    auto alloc = [&](size_t bytes) -> char* {
        char* p = w + off;
        off += (bytes + 255) & ~(size_t)255;
        return p;
    };
    int*   cnt    = (int*)  alloc((size_t)N * 4);
    int*   fillc  = (int*)  alloc((size_t)N * 4);   // adjacent to cnt
    int*   pcnt   = (int*)  alloc(256);             // adjacent: one memset covers all
    int*   offs   = (int*)  alloc((size_t)(N + 1) * 4);
    float* dinv   = (float*)alloc((size_t)MPAD * 4); // padded: epilogues read r<MPAD
    int*   flag   = (int*)  alloc(256);
    int*   bsum   = (int*)  alloc(256);
    int*   bbase  = (int*)  alloc(256);
    const int partcap = E / 4;                       // 2x expected partition size
    int2*  epart  = (int2*) alloc((size_t)8 * partcap * 8);
    int*   rowidx = (int*)  alloc((size_t)E * 4);    // no memset: every slot written
    unsigned short* Bt1 = (unsigned short*)alloc((size_t)HID * KP1 * 2);
    unsigned short* Bt2 = (unsigned short*)alloc((size_t)HID * HID * 2);
    unsigned short* Bt3 = (unsigned short*)alloc((size_t)NP3 * HID * 2);
    unsigned short* bufA = (unsigned short*)alloc((size_t)MPAD * HID * 2);
    unsigned short* bufB = (unsigned short*)alloc((size_t)MPAD * HID * 2);
    unsigned short* Xs  = bufA;    // prep out
    unsigned short* Y1  = bufB;    // aggx out
    unsigned short* H1s = bufA;    // gemm1 out (Xs dead)
    unsigned short* Y2  = bufB;    // agg256s out (Y1 dead)
    unsigned short* G3  = bufA;    // mlp23 out (H1s dead)

    // one memset covers cnt + fillc + pcnt (contiguous in ws)
    size_t msz = (size_t)((char*)pcnt - (char*)cnt) + 256;
    (void)hipMemsetAsync(cnt, 0, msz, stream);

    const int rng = (N + 7) / 8;             // dest-eighth length
    const int nsc = (N + 4095) / 4096;       // scan blocks
    const int pgrid = 8 * ((partcap + 255) / 256);

    k_detect<<<1, 64, 0, stream>>>(ei, flag, N);
    k_part<<<(E + 2047) / 2048, 256, 0, stream>>>(ei, flag, epart, pcnt, cnt, E, N, rng, partcap);
    k_scanA<<<nsc, 1024, 0, stream>>>(cnt, bsum, N);
    k_scanB<<<1, 64, 0, stream>>>(bsum, bbase, offs, nsc, N);
    k_scanC<<<nsc, 1024, 0, stream>>>(cnt, bbase, offs, dinv, N);
    k_fill8p<<<pgrid, 256, 0, stream>>>(epart, pcnt, offs, fillc, rowidx, E, partcap);

    int prep_grid = (N * KP1 + 255) / 256 + (HID * KP1) / 256 + (HID * HID) / 256 + (NP3 * HID) / 256;
    k_prep<<<prep_grid, 256, 0, stream>>>(x, dinv, Xs, W1, Bt1, W2, Bt2, W3, Bt3, N);

    // layer 1: aggregate-first, then GEMM (+b1, relu, *dinv)
    k_aggx<<<(N + 31) / 32, 256, 0, stream>>>(Xs, offs, rowidx, dinv, Y1, N);
    dim3 g1(MPAD / 128, HID / 128);
    k_gemm_lds<<<g1, 256, 0, stream>>>(Y1, Bt1, dinv, b1, H1s, KP1, HID, 1, 1, 1);
    // layer 2 aggregate (chunk x half cells), then fused GEMM2+GEMM3
    int half_n = (N + 1) / 2;
    int bpc2 = (half_n + 31) / 32;
    k_agg256s<<<8 * bpc2, 256, 0, stream>>>(H1s, offs, rowidx, dinv, Y2, N, half_n);
    k_mlp23<<<MPAD / 128, 256, 0, stream>>>(Y2, Bt2, Bt3, b2, dinv, G3);
    // layer 3 aggregate (+b3), f32 out (chunk x quarter cells)
    int quar_n = (N + 3) / 4;
    int bpc3 = (quar_n + 31) / 32;
    k_aggouts<<<8 * bpc3, 256, 0, stream>>>(G3, offs, rowidx, dinv, b3, out, N, quar_n);

    (void)n_in; (void)out_size; (void)ws_size;
}

// Round 11
// 558.645 us; speedup vs baseline: 1.3192x; 1.3192x over previous
//
#include <hip/hip_runtime.h>

// GCN 3-layer forward on MI355X.
// Pipeline (A_hat (X W) = (A_hat X) W):
//   aggx:  Y1 = A_hat X          GEMM1: H1s = dinv*relu(Y1 W1 + b1)
//   agg256s: Y2 = A_hat H1       MLP23: G3 = dinv*((relu(Y2 W2 + b2)) W3)  [fused]
//   aggouts: out = dinv[c]*(sum G3[r]+G3[c]) + b3 (f32)
// Gather wall (r0-r10): L2-fill path ~3.6-3.8 TB/s; FETCH at capacity floor.
// Fetch granule 128B (r4). XCD cell map bid&7 (r3/r6-validated, reads+writes).
// Closed theories: 64B granule (r4: 2x worse), seg-lockstep (r7: drift),
// reg-fused gather+GEMM (r2: occupancy), NT hints (r10: NT stores bypass L2
// write-combining -> 7.5x write amplification on aggouts; stream pollution
// negligible -- FETCH unchanged). ALL NT hints reverted this round.
// Kept from r9/r10: count fused into k_part (k_count8 deleted).
// k_part: block radix partition by dest-eighth, LDS-staged, compacted runs.
// k_fill8p: cell reads its partition, writes its rowidx region (XCD-local,
// full-line writeback; r6-proven).
// MLP23 fusion: H2 tile in LDS (XOR-swizzle (row&7)<<4); W3 L2-resident.

#define IN_F 50
#define HID  256
#define OUT_F 121
#define KP1  64      // layer-1 width padded 50->64
#define NP3  128     // layer-3 N padded 121->128
#define MPAD 100096  // 782 * 128

typedef __attribute__((ext_vector_type(8))) short bf16x8;
typedef __attribute__((ext_vector_type(4))) float f32x4;

__device__ __forceinline__ float bf2f(unsigned short u) {
    union { unsigned int i; float f; } x; x.i = ((unsigned int)u) << 16; return x.f;
}
__device__ __forceinline__ unsigned short f2bf(float f) {
    union { float f; unsigned int i; } x; x.f = f;
    unsigned int r = x.i + 0x7FFFu + ((x.i >> 16) & 1u);  // RNE
    return (unsigned short)(r >> 16);
}

__device__ __forceinline__ void gl2lds16(const void* g, void* l) {
    __builtin_amdgcn_global_load_lds(
        (const __attribute__((address_space(1))) void*)g,
        (__attribute__((address_space(3))) void*)l, 16, 0, 0);
}

// ---- edge dtype detection (int64 vs int32), 64-lane parallel ----------------
__global__ void k_detect(const int* __restrict__ ei, int* __restrict__ flag, int N) {
    int i = threadIdx.x;
    int lo = ei[2 * i], hi = ei[2 * i + 1];
    int bad = (hi != 0) || ((unsigned)lo >= (unsigned)N);
    unsigned long long m = __ballot(bad);
    if (threadIdx.x == 0) *flag = (m == 0ULL) ? 1 : 0;
}

// ---- k_part: radix partition of edges by dest-eighth + fused dest count -----
// 2048 edges/block via LDS; compacted flushes (~2KB runs -> full-line writes).
__global__ __launch_bounds__(256) void k_part(const int* __restrict__ ei,
                                              const int* __restrict__ flag,
                                              int2* __restrict__ epart,
                                              int* __restrict__ pcnt,
                                              int* __restrict__ cnt,
                                              int E, int N, int rng, int partcap) {
    __shared__ int2 eb[2048];
    __shared__ int hist[8], base[8], cur[8];
    int tid = threadIdx.x;
    if (tid < 8) { hist[tid] = 0; cur[tid] = 0; }
    __syncthreads();
    int f = *flag;
    int t0 = blockIdx.x * 2048;
    #pragma unroll
    for (int j = 0; j < 8; j++) {
        int t = t0 + j * 256 + tid;
        int2 e = make_int2(-1, -1);
        if (t < E) {
            int c = f ? ei[2 * (E + t)] : ei[E + t];
            int r = f ? ei[2 * t] : ei[t];
            e.x = min(max(c, 0), N - 1);
            e.y = min(max(r, 0), N - 1);
            atomicAdd(&hist[e.x / rng], 1);
        }
        eb[j * 256 + tid] = e;
    }
    __syncthreads();
    if (tid < 8) base[tid] = atomicAdd(&pcnt[tid], hist[tid]);
    __syncthreads();
    #pragma unroll
    for (int j = 0; j < 8; j++) {
        int2 e = eb[j * 256 + tid];
        if (e.x >= 0) {
            int rg = e.x / rng;
            int p = base[rg] + atomicAdd(&cur[rg], 1);
            if (p < partcap) {
                epart[(size_t)rg * partcap + p] = e;
                atomicAdd(&cnt[e.x], 1);
            }
        }
    }
}

// ---- 3-phase parallel scan over cnt[N] --------------------------------------
__global__ __launch_bounds__(1024) void k_scanA(const int* __restrict__ cnt,
                                                int* __restrict__ bsum, int n) {
    __shared__ int ws[16];
    int tid = threadIdx.x, lane = tid & 63, wid = tid >> 6;
    int i0 = blockIdx.x * 4096 + tid * 4;
    int t = 0;
    #pragma unroll
    for (int j = 0; j < 4; j++) t += (i0 + j < n) ? cnt[i0 + j] : 0;
    #pragma unroll
    for (int d = 1; d < 64; d <<= 1) t += __shfl_xor(t, d, 64);
    if (lane == 0) ws[wid] = t;
    __syncthreads();
    if (tid == 0) {
        int s = 0;
        #pragma unroll
        for (int j = 0; j < 16; j++) s += ws[j];
        bsum[blockIdx.x] = s;
    }
}

__global__ void k_scanB(const int* __restrict__ bsum, int* __restrict__ bbase,
                        int* __restrict__ offs, int nb, int n) {
    int lane = threadIdx.x;
    int v = (lane < nb) ? bsum[lane] : 0;
    int x = v;
    #pragma unroll
    for (int d = 1; d < 64; d <<= 1) { int y = __shfl_up(x, d, 64); if (lane >= d) x += y; }
    if (lane < nb) bbase[lane] = x - v;
    if (lane == nb - 1) offs[n] = x;
}

__global__ __launch_bounds__(1024) void k_scanC(const int* __restrict__ cnt,
                                                const int* __restrict__ bbase,
                                                int* __restrict__ offs,
                                                float* __restrict__ dinv, int n) {
    __shared__ int wsum[16];
    int tid = threadIdx.x, lane = tid & 63, wid = tid >> 6;
    int i0 = blockIdx.x * 4096 + tid * 4;
    int v0 = (i0 + 0 < n) ? cnt[i0 + 0] : 0;
    int v1 = (i0 + 1 < n) ? cnt[i0 + 1] : 0;
    int v2 = (i0 + 2 < n) ? cnt[i0 + 2] : 0;
    int v3 = (i0 + 3 < n) ? cnt[i0 + 3] : 0;
    int s1 = v0 + v1, s2 = s1 + v2, tsum = s2 + v3;
    int x = tsum;
    #pragma unroll
    for (int d = 1; d < 64; d <<= 1) { int y = __shfl_up(x, d, 64); if (lane >= d) x += y; }
    if (lane == 63) wsum[wid] = x;
    __syncthreads();
    int wpre = 0;
    #pragma unroll
    for (int j = 0; j < 16; j++) wpre += (j < wid) ? wsum[j] : 0;
    int e0 = bbase[blockIdx.x] + wpre + x - tsum;
    if (i0 + 0 < n) { offs[i0+0] = e0;      dinv[i0+0] = rsqrtf((float)(v0 + 1)); }
    if (i0 + 1 < n) { offs[i0+1] = e0 + v0; dinv[i0+1] = rsqrtf((float)(v1 + 1)); }
    if (i0 + 2 < n) { offs[i0+2] = e0 + s1; dinv[i0+2] = rsqrtf((float)(v2 + 1)); }
    if (i0 + 3 < n) { offs[i0+3] = e0 + s2; dinv[i0+3] = rsqrtf((float)(v3 + 1)); }
}

// ---- fill: cell = bid&7 reads its partition, writes its rowidx region -------
__global__ void k_fill8p(const int2* __restrict__ epart, const int* __restrict__ pcnt,
                         const int* __restrict__ offs, int* __restrict__ fillc,
                         int* __restrict__ rowidx, int E, int partcap) {
    int cell = blockIdx.x & 7;
    int t = (blockIdx.x >> 3) * blockDim.x + threadIdx.x;
    if (t >= min(pcnt[cell], partcap)) return;
    int2 e = epart[(size_t)cell * partcap + t];
    int pos = offs[e.x] + atomicAdd(&fillc[e.x], 1);
    if ((unsigned)pos < (unsigned)E) rowidx[pos] = e.y;
}

// ---- input prep (padx + 3 weight transposes, one launch) --------------------
__global__ void k_prep(const float* __restrict__ x, const float* __restrict__ dinv,
                       unsigned short* __restrict__ Xs,
                       const float* __restrict__ W1, unsigned short* __restrict__ Bt1,
                       const float* __restrict__ W2, unsigned short* __restrict__ Bt2,
                       const float* __restrict__ W3, unsigned short* __restrict__ Bt3,
                       int N) {
    int bid = blockIdx.x;
    int npadx = (N * KP1 + 255) / 256;
    if (bid < npadx) {
        int idx = bid * 256 + (int)threadIdx.x;
        if (idx < N * KP1) {
            int node = idx >> 6, k = idx & 63;
            Xs[idx] = (k < IN_F) ? f2bf(dinv[node] * x[node * IN_F + k]) : (unsigned short)0;
        }
        return;
    }
    bid -= npadx;
    if (bid < (HID * KP1) / 256) {          // Bt1 [256][64]
        int idx = bid * 256 + (int)threadIdx.x;
        int nn = idx >> 6, k = idx & 63;
        Bt1[idx] = (k < IN_F) ? f2bf(W1[k * HID + nn]) : (unsigned short)0;
        return;
    }
    bid -= (HID * KP1) / 256;
    if (bid < (HID * HID) / 256) {          // Bt2 [256][256]
        int idx = bid * 256 + (int)threadIdx.x;
        int nn = idx >> 8, k = idx & 255;
        Bt2[idx] = f2bf(W2[k * HID + nn]);
        return;
    }
    bid -= (HID * HID) / 256;
    {                                        // Bt3 [128][256]
        int idx = bid * 256 + (int)threadIdx.x;
        int nn = idx >> 8, k = idx & 255;
        Bt3[idx] = (nn < OUT_F) ? f2bf(W3[k * OUT_F + nn]) : (unsigned short)0;
    }
}

// ---- LDS-tiled GEMM (m97 structure) — layer 1 only --------------------------
__global__ __launch_bounds__(256) void k_gemm_lds(const unsigned short* __restrict__ A,
                                                  const unsigned short* __restrict__ Bt,
                                                  const float* __restrict__ dinv,
                                                  const float* __restrict__ bias,
                                                  unsigned short* __restrict__ C,
                                                  int K, int Nout,
                                                  int BIAS, int RELU, int SCALE) {
    __shared__ char lds[16384];   // A tile [128][32] bf16 @0, B tile @8192
    const int tid = threadIdx.x;
    const int wid = tid >> 6, lane = tid & 63;
    const int wm = wid & 1, wn = wid >> 1;
    const int quad = lane >> 4, ml = lane & 15;
    const int m0 = blockIdx.x * 128;
    const int n0g = blockIdx.y * 128;

    f32x4 acc[4][4];
    #pragma unroll
    for (int a = 0; a < 4; a++)
        #pragma unroll
        for (int b = 0; b < 4; b++) acc[a][b] = (f32x4){0.f, 0.f, 0.f, 0.f};

    for (int kk = 0; kk < K; kk += 32) {
        #pragma unroll
        for (int r = 0; r < 2; r++) {
            int c = r * 256 + tid;
            int row = c >> 2, q = c & 3;
            gl2lds16(A  + (size_t)(m0  + row) * K + kk + q * 8, lds + c * 16);
            gl2lds16(Bt + (size_t)(n0g + row) * K + kk + q * 8, lds + 8192 + c * 16);
        }
        __syncthreads();
        bf16x8 af[4], bfv[4];
        #pragma unroll
        for (int mf = 0; mf < 4; mf++)
            af[mf] = *(const bf16x8*)(lds + ((wm * 64 + mf * 16 + ml) * 64 + quad * 16));
        #pragma unroll
        for (int nf = 0; nf < 4; nf++)
            bfv[nf] = *(const bf16x8*)(lds + 8192 + ((wn * 64 + nf * 16 + ml) * 64 + quad * 16));
        #pragma unroll
        for (int mf = 0; mf < 4; mf++)
            #pragma unroll
            for (int nf = 0; nf < 4; nf++)
                acc[mf][nf] = __builtin_amdgcn_mfma_f32_16x16x32_bf16(af[mf], bfv[nf], acc[mf][nf], 0, 0, 0);
        __syncthreads();
    }

    #pragma unroll
    for (int mf = 0; mf < 4; mf++) {
        int r0 = m0 + wm * 64 + mf * 16 + quad * 4;
        float dd[4] = {1.f, 1.f, 1.f, 1.f};
        if (SCALE) { dd[0]=dinv[r0]; dd[1]=dinv[r0+1]; dd[2]=dinv[r0+2]; dd[3]=dinv[r0+3]; }
        #pragma unroll
        for (int nf = 0; nf < 4; nf++) {
            int col = n0g + wn * 64 + nf * 16 + ml;
            float bb = BIAS ? bias[col] : 0.f;
            #pragma unroll
            for (int i = 0; i < 4; i++) {
                float v = acc[mf][nf][i] + bb;
                if (RELU) v = fmaxf(v, 0.f);
                v *= dd[i];
                C[(size_t)(r0 + i) * Nout + col] = f2bf(v);
            }
        }
    }
}

// ---- FUSED GEMM2+GEMM3: G3 = dinv * (relu(Y2 W2 + b2) W3) -------------------
__global__ __launch_bounds__(256) void k_mlp23(const unsigned short* __restrict__ A,
                                               const unsigned short* __restrict__ B2t,
                                               const unsigned short* __restrict__ B3t,
                                               const float* __restrict__ b2,
                                               const float* __restrict__ dinv,
                                               unsigned short* __restrict__ G) {
    __shared__ char lds[65536];  // phase1 staging: A[128][32]@0, B2[256][32]@8192 (24KB)
                                 // then H2 [128][256] bf16 @0 (64KB, swizzled)
    const int tid = threadIdx.x;
    const int wid = tid >> 6, lane = tid & 63;
    const int wm = wid & 1, wn = wid >> 1;
    const int quad = lane >> 4, ml = lane & 15;
    const int m0 = blockIdx.x * 128;

    f32x4 acc1[4][8];
    #pragma unroll
    for (int a = 0; a < 4; a++)
        #pragma unroll
        for (int b = 0; b < 8; b++) acc1[a][b] = (f32x4){0.f, 0.f, 0.f, 0.f};

    for (int kk = 0; kk < HID; kk += 32) {
        #pragma unroll
        for (int r = 0; r < 2; r++) {
            int c = r * 256 + tid;
            int row = c >> 2, q = c & 3;
            gl2lds16(A + (size_t)(m0 + row) * HID + kk + q * 8, lds + c * 16);
        }
        #pragma unroll
        for (int r = 0; r < 4; r++) {
            int c = r * 256 + tid;
            int nn = c >> 2, q = c & 3;
            gl2lds16(B2t + (size_t)nn * HID + kk + q * 8, lds + 8192 + c * 16);
        }
        __syncthreads();
        bf16x8 af[4], bv[8];
        #pragma unroll
        for (int mf = 0; mf < 4; mf++)
            af[mf] = *(const bf16x8*)(lds + ((wm * 64 + mf * 16 + ml) * 64 + quad * 16));
        #pragma unroll
        for (int nf = 0; nf < 8; nf++)
            bv[nf] = *(const bf16x8*)(lds + 8192 + ((wn * 128 + nf * 16 + ml) * 64 + quad * 16));
        #pragma unroll
        for (int mf = 0; mf < 4; mf++)
            #pragma unroll
            for (int nf = 0; nf < 8; nf++)
                acc1[mf][nf] = __builtin_amdgcn_mfma_f32_16x16x32_bf16(af[mf], bv[nf], acc1[mf][nf], 0, 0, 0);
        __syncthreads();
    }

    // H2 = relu(acc1 + b2) -> LDS bf16, swizzled byte ^= (row&7)<<4
    #pragma unroll
    for (int nf = 0; nf < 8; nf++) {
        int col = wn * 128 + nf * 16 + ml;
        float bb = b2[col];
        #pragma unroll
        for (int mf = 0; mf < 4; mf++) {
            int rl = wm * 64 + mf * 16 + quad * 4;
            #pragma unroll
            for (int i = 0; i < 4; i++) {
                int row = rl + i;
                int byte = (row * 512 + col * 2) ^ ((row & 7) << 4);
                *(unsigned short*)(lds + byte) = f2bf(fmaxf(acc1[mf][nf][i] + bb, 0.f));
            }
        }
    }
    __syncthreads();

    // phase 2: G3 tile (128x128), A from H2-LDS, B direct from global Bt3
    f32x4 acc2[4][4];
    #pragma unroll
    for (int a = 0; a < 4; a++)
        #pragma unroll
        for (int b = 0; b < 4; b++) acc2[a][b] = (f32x4){0.f, 0.f, 0.f, 0.f};

    for (int kk = 0; kk < HID; kk += 32) {
        bf16x8 af2[4], bv2[4];
        #pragma unroll
        for (int mf = 0; mf < 4; mf++) {
            int row = wm * 64 + mf * 16 + ml;
            int byte = (row * 512 + kk * 2 + quad * 16) ^ ((row & 7) << 4);
            af2[mf] = *(const bf16x8*)(lds + byte);
        }
        #pragma unroll
        for (int nf = 0; nf < 4; nf++)
            bv2[nf] = *(const bf16x8*)(B3t + (size_t)(wn * 64 + nf * 16 + ml) * HID + kk + quad * 8);
        #pragma unroll
        for (int mf = 0; mf < 4; mf++)
            #pragma unroll
            for (int nf = 0; nf < 4; nf++)
                acc2[mf][nf] = __builtin_amdgcn_mfma_f32_16x16x32_bf16(af2[mf], bv2[nf], acc2[mf][nf], 0, 0, 0);
    }

    #pragma unroll
    for (int mf = 0; mf < 4; mf++) {
        int r0 = m0 + wm * 64 + mf * 16 + quad * 4;
        float dd[4] = {dinv[r0], dinv[r0+1], dinv[r0+2], dinv[r0+3]};
        #pragma unroll
        for (int nf = 0; nf < 4; nf++) {
            int col = wn * 64 + nf * 16 + ml;
            #pragma unroll
            for (int i = 0; i < 4; i++)
                G[(size_t)(r0 + i) * NP3 + col] = f2bf(acc2[mf][nf][i] * dd[i]);
        }
    }
}

// ---- aggregation kernels (r8-proven: plain cached loads/stores) -------------
// 16B/lane gathers, masked unroll-4 edge loop (tail lanes re-read last edge row
// -> L1 hit; fma-masked with 0).

// aggx: rows 64 bf16 = 128B (1 line, no split) -> 8 lanes/row, 8 nodes/wave.
__global__ void k_aggx(const unsigned short* __restrict__ Xs,
                       const int* __restrict__ offs, const int* __restrict__ rowidx,
                       const float* __restrict__ dinv, unsigned short* __restrict__ Y, int N) {
    int wid = threadIdx.x >> 6, lane = threadIdx.x & 63;
    int sub = lane >> 3, sl = lane & 7;
    int node = blockIdx.x * 32 + wid * 8 + sub;
    int nc = min(node, N - 1);
    int c = sl * 8;
    bf16x8 s = *(const bf16x8*)(Xs + (size_t)nc * KP1 + c);
    float a[8];
    #pragma unroll
    for (int k = 0; k < 8; k++) a[k] = bf2f((unsigned short)s[k]);
    int e = offs[nc], end = offs[nc + 1];
    if (node >= N) { e = 0; end = 0; }
    while (__any(e < end)) {
        int r[4]; float m[4];
        #pragma unroll
        for (int j = 0; j < 4; j++) {
            int idx = e + j;
            m[j] = (idx < end) ? 1.f : 0.f;
            idx = min(idx, end - 1); idx = max(idx, 0);
            r[j] = rowidx[idx];
        }
        bf16x8 u[4];
        #pragma unroll
        for (int j = 0; j < 4; j++)
            u[j] = *(const bf16x8*)(Xs + (size_t)r[j] * KP1 + c);
        #pragma unroll
        for (int j = 0; j < 4; j++)
            #pragma unroll
            for (int k = 0; k < 8; k++)
                a[k] = fmaf(bf2f((unsigned short)u[j][k]), m[j], a[k]);
        e += 4;
    }
    if (node < N) {
        float dv = dinv[node];
        bf16x8 o;
        #pragma unroll
        for (int k = 0; k < 8; k++) o[k] = (short)f2bf(a[k] * dv);
        *(bf16x8*)(Y + (size_t)node * KP1 + c) = o;
    }
}

// agg256s: FEATURE-SPLIT gather, 256-wide rows. 4 chunks of 64 bf16 (128B line);
// cell = bid&7: chunk = cell>>1, dest-half = cell&1. 8 lanes/chunk-row,
// 8 nodes/wave, 32/block. Per-XCD slab 12.8MB (r6-proven: 107us, FETCH ~329MB).
__global__ void k_agg256s(const unsigned short* __restrict__ Hn,
                          const int* __restrict__ offs, const int* __restrict__ rowidx,
                          const float* __restrict__ dinv, unsigned short* __restrict__ Y,
                          int N, int half_n) {
    int cell = blockIdx.x & 7;
    int chunk = cell >> 1, half = cell & 1;
    int idx = blockIdx.x >> 3;
    int wid = threadIdx.x >> 6, lane = threadIdx.x & 63;
    int sub = lane >> 3, sl = lane & 7;
    int node = half * half_n + idx * 32 + wid * 8 + sub;
    int hi_end = min((half + 1) * half_n, N);
    int ok = node < hi_end;
    int nc = ok ? node : hi_end - 1;
    int c = chunk * 64 + sl * 8;
    bf16x8 s = *(const bf16x8*)(Hn + (size_t)nc * HID + c);
    float a[8];
    #pragma unroll
    for (int k = 0; k < 8; k++) a[k] = bf2f((unsigned short)s[k]);
    int e = offs[nc], end = offs[nc + 1];
    if (!ok) { e = 0; end = 0; }
    while (__any(e < end)) {
        int r[4]; float m[4];
        #pragma unroll
        for (int j = 0; j < 4; j++) {
            int idx2 = e + j;
            m[j] = (idx2 < end) ? 1.f : 0.f;
            idx2 = min(idx2, end - 1); idx2 = max(idx2, 0);
            r[j] = rowidx[idx2];
        }
        bf16x8 u[4];
        #pragma unroll
        for (int j = 0; j < 4; j++)
            u[j] = *(const bf16x8*)(Hn + (size_t)r[j] * HID + c);
        #pragma unroll
        for (int j = 0; j < 4; j++)
            #pragma unroll
            for (int k = 0; k < 8; k++)
                a[k] = fmaf(bf2f((unsigned short)u[j][k]), m[j], a[k]);
        e += 4;
    }
    if (ok) {
        float dv = dinv[node];
        bf16x8 o;
        #pragma unroll
        for (int k = 0; k < 8; k++) o[k] = (short)f2bf(a[k] * dv);
        *(bf16x8*)(Y + (size_t)node * HID + c) = o;
    }
}

// aggouts: FEATURE-SPLIT gather, 128-wide rows. 2 chunks of 64 bf16 (128B line)
// x 4 dest-quarters; cell = bid&7: chunk = cell>>2, quarter = cell&3.
// Per-XCD slab 3.2MB -- fits L2 (r3-proven).
__global__ void k_aggouts(const unsigned short* __restrict__ G,
                          const int* __restrict__ offs, const int* __restrict__ rowidx,
                          const float* __restrict__ dinv, const float* __restrict__ bias,
                          float* __restrict__ out, int N, int quar_n) {
    int cell = blockIdx.x & 7;
    int chunk = cell >> 2, quar = cell & 3;
    int idx = blockIdx.x >> 3;
    int wid = threadIdx.x >> 6, lane = threadIdx.x & 63;
    int sub = lane >> 3, sl = lane & 7;
    int node = quar * quar_n + idx * 32 + wid * 8 + sub;
    int hi_end = min((quar + 1) * quar_n, N);
    int ok = node < hi_end;
    int nc = ok ? node : hi_end - 1;
    int c = chunk * 64 + sl * 8;
    bf16x8 s = *(const bf16x8*)(G + (size_t)nc * NP3 + c);
    float a[8];
    #pragma unroll
    for (int k = 0; k < 8; k++) a[k] = bf2f((unsigned short)s[k]);
    int e = offs[nc], end = offs[nc + 1];
    if (!ok) { e = 0; end = 0; }
    while (__any(e < end)) {
        int r[4]; float m[4];
        #pragma unroll
        for (int j = 0; j < 4; j++) {
            int idx2 = e + j;
            m[j] = (idx2 < end) ? 1.f : 0.f;
            idx2 = min(idx2, end - 1); idx2 = max(idx2, 0);
            r[j] = rowidx[idx2];
        }
        bf16x8 u[4];
        #pragma unroll
        for (int j = 0; j < 4; j++)
            u[j] = *(const bf16x8*)(G + (size_t)r[j] * NP3 + c);
        #pragma unroll
        for (int j = 0; j < 4; j++)
            #pragma unroll
            for (int k = 0; k < 8; k++)
                a[k] = fmaf(bf2f((unsigned short)u[j][k]), m[j], a[k]);
        e += 4;
    }
    if (ok) {
        float dv = dinv[node];
        #pragma unroll
        for (int k = 0; k < 8; k++) {
            int col = c + k;
            if (col < OUT_F)
                out[(size_t)node * OUT_F + col] = fmaf(a[k], dv, bias[col]);
        }
    }
}

// ---- launch -----------------------------------------------------------------

extern "C" void kernel_launch(void* const* d_in, const int* in_sizes, int n_in,
                              void* d_out, int out_size, void* d_ws, size_t ws_size,
                              hipStream_t stream) {
    const float* x  = (const float*)d_in[0];
    const int*   ei = (const int*)d_in[1];
    const float* W1 = (const float*)d_in[2];
    const float* b1 = (const float*)d_in[3];
    const float* W2 = (const float*)d_in[4];
    const float* b2 = (const float*)d_in[5];
    const float* W3 = (const float*)d_in[6];
    const float* b3 = (const float*)d_in[7];
    float* out = (float*)d_out;

    const int N = in_sizes[0] / IN_F;     // 100000
    const int E = in_sizes[1] / 2;        // 1600000

    char* w = (char*)d_ws;
    size_t off = 0;
    auto alloc = [&](size_t bytes) -> char* {
        char* p = w + off;
        off += (bytes + 255) & ~(size_t)255;
        return p;
    };
    int*   cnt    = (int*)  alloc((size_t)N * 4);
    int*   fillc  = (int*)  alloc((size_t)N * 4);   // adjacent to cnt
    int*   pcnt   = (int*)  alloc(256);             // adjacent: one memset covers all
    int*   offs   = (int*)  alloc((size_t)(N + 1) * 4);
    float* dinv   = (float*)alloc((size_t)MPAD * 4); // padded: epilogues read r<MPAD
    int*   flag   = (int*)  alloc(256);
    int*   bsum   = (int*)  alloc(256);
    int*   bbase  = (int*)  alloc(256);
    const int partcap = E / 4;                       // 2x expected partition size
    int2*  epart  = (int2*) alloc((size_t)8 * partcap * 8);
    int*   rowidx = (int*)  alloc((size_t)E * 4);    // no memset: every slot written
    unsigned short* Bt1 = (unsigned short*)alloc((size_t)HID * KP1 * 2);
    unsigned short* Bt2 = (unsigned short*)alloc((size_t)HID * HID * 2);
    unsigned short* Bt3 = (unsigned short*)alloc((size_t)NP3 * HID * 2);
    unsigned short* bufA = (unsigned short*)alloc((size_t)MPAD * HID * 2);
    unsigned short* bufB = (unsigned short*)alloc((size_t)MPAD * HID * 2);
    unsigned short* Xs  = bufA;    // prep out
    unsigned short* Y1  = bufB;    // aggx out
    unsigned short* H1s = bufA;    // gemm1 out (Xs dead)
    unsigned short* Y2  = bufB;    // agg256s out (Y1 dead)
    unsigned short* G3  = bufA;    // mlp23 out (H1s dead)

    // one memset covers cnt + fillc + pcnt (contiguous in ws)
    size_t msz = (size_t)((char*)pcnt - (char*)cnt) + 256;
    (void)hipMemsetAsync(cnt, 0, msz, stream);

    const int rng = (N + 7) / 8;             // dest-eighth length
    const int nsc = (N + 4095) / 4096;       // scan blocks
    const int pgrid = 8 * ((partcap + 255) / 256);

    k_detect<<<1, 64, 0, stream>>>(ei, flag, N);
    k_part<<<(E + 2047) / 2048, 256, 0, stream>>>(ei, flag, epart, pcnt, cnt, E, N, rng, partcap);
    k_scanA<<<nsc, 1024, 0, stream>>>(cnt, bsum, N);
    k_scanB<<<1, 64, 0, stream>>>(bsum, bbase, offs, nsc, N);
    k_scanC<<<nsc, 1024, 0, stream>>>(cnt, bbase, offs, dinv, N);
    k_fill8p<<<pgrid, 256, 0, stream>>>(epart, pcnt, offs, fillc, rowidx, E, partcap);

    int prep_grid = (N * KP1 + 255) / 256 + (HID * KP1) / 256 + (HID * HID) / 256 + (NP3 * HID) / 256;
    k_prep<<<prep_grid, 256, 0, stream>>>(x, dinv, Xs, W1, Bt1, W2, Bt2, W3, Bt3, N);

    // layer 1: aggregate-first, then GEMM (+b1, relu, *dinv)
    k_aggx<<<(N + 31) / 32, 256, 0, stream>>>(Xs, offs, rowidx, dinv, Y1, N);
    dim3 g1(MPAD / 128, HID / 128);
    k_gemm_lds<<<g1, 256, 0, stream>>>(Y1, Bt1, dinv, b1, H1s, KP1, HID, 1, 1, 1);
    // layer 2 aggregate (chunk x half cells), then fused GEMM2+GEMM3
    int half_n = (N + 1) / 2;
    int bpc2 = (half_n + 31) / 32;
    k_agg256s<<<8 * bpc2, 256, 0, stream>>>(H1s, offs, rowidx, dinv, Y2, N, half_n);
    k_mlp23<<<MPAD / 128, 256, 0, stream>>>(Y2, Bt2, Bt3, b2, dinv, G3);
    // layer 3 aggregate (+b3), f32 out (chunk x quarter cells)
    int quar_n = (N + 3) / 4;
    int bpc3 = (quar_n + 31) / 32;
    k_aggouts<<<8 * bpc3, 256, 0, stream>>>(G3, offs, rowidx, dinv, b3, out, N, quar_n);

    (void)n_in; (void)out_size; (void)ws_size;
}